// Round 9
// baseline (243.539 us; speedup 1.0000x reference)
//
#include <hip/hip_runtime.h>
#include <float.h>
#include <math.h>

// Problem constants (fixed by setup_inputs)
#define B_Q   2048
#define N_S   16384
#define DIM   512
#define C_CLS 17
#define K_TOP 8
#define TAU_F 10.0f
#define EPSF  1e-12f

typedef _Float16 f16x8 __attribute__((ext_vector_type(8)));
typedef float    f32x16 __attribute__((ext_vector_type(16)));

// ---- workspace layout (in floats) ----
// Split-f16 arrays are TILED: element (row n, k) lives at
//   [(k>>3)*NROWS + n]*8 + (k&7)  -> fragment loads are 16B/lane coalesced.
#define WS_YY     0            // N                        -> 16384
#define WS_CLS    16384        // N (int)                  -> 32768
#define WS_P      32768        // N*17                     -> 311296
#define WS_CNH    311296       // 64*32*8 f16 = 8192 fl    -> 319488
#define WS_CNL    319488       // 8192 fl                  -> 327680
#define WS_CAND   327680       // u64[2048][1024]          -> 4521984
#define WS_ZNH    4521984      // B*D f16 tiled (524288)   -> 5046272
#define WS_ZNL    5046272      //                          -> 5570560
#define WS_SUPH   5570560      // N*D f16 tiled (4194304)  -> 9764864
#define WS_SUPL   9764864      //                          -> 13959168
// total 13,959,168 floats = 55.8 MB
// centroid partials alias into cand region (consumed before cands exist):
#define WS_PARTA  WS_CAND                 // 256 * 8704 = 2228224
#define WS_PCNTA  (WS_CAND + 2228224)     // 256 * 32

// ======================= u64 sort-network helpers =======================
__device__ __forceinline__ void csd(unsigned long long& a, unsigned long long& b) {
    const bool c = a > b;
    const unsigned long long mx = c ? a : b;
    const unsigned long long mn = c ? b : a;
    a = mx; b = mn;
}

__device__ __forceinline__ void sort8d(unsigned long long k[8]) {
    csd(k[0],k[1]); csd(k[2],k[3]); csd(k[4],k[5]); csd(k[6],k[7]);
    csd(k[0],k[2]); csd(k[1],k[3]); csd(k[4],k[6]); csd(k[5],k[7]);
    csd(k[1],k[2]); csd(k[5],k[6]);
    csd(k[0],k[4]); csd(k[1],k[5]); csd(k[2],k[6]); csd(k[3],k[7]);
    csd(k[2],k[4]); csd(k[3],k[5]);
    csd(k[1],k[2]); csd(k[3],k[4]); csd(k[5],k[6]);
}

__device__ __forceinline__ void mrg8d(unsigned long long a[8],
                                      const unsigned long long b[8]) {
    unsigned long long m[8];
    #pragma unroll
    for (int i = 0; i < 8; ++i) {
        const unsigned long long x = b[7 - i];
        m[i] = a[i] > x ? a[i] : x;
    }
    csd(m[0],m[4]); csd(m[1],m[5]); csd(m[2],m[6]); csd(m[3],m[7]);
    csd(m[0],m[2]); csd(m[1],m[3]); csd(m[4],m[6]); csd(m[5],m[7]);
    csd(m[0],m[1]); csd(m[2],m[3]); csd(m[4],m[5]); csd(m[6],m[7]);
    #pragma unroll
    for (int i = 0; i < 8; ++i) a[i] = m[i];
}

__device__ __forceinline__ unsigned long long shfl_xor_u64(unsigned long long v, int m) {
    unsigned int lo = (unsigned int)v, hi = (unsigned int)(v >> 32);
    lo = __shfl_xor(lo, m, 64);
    hi = __shfl_xor(hi, m, 64);
    return ((unsigned long long)hi << 32) | lo;
}

__device__ __forceinline__ unsigned int f32_sortable(float f) {
    unsigned int u = __float_as_uint(f);
    u ^= (unsigned int)((int)u >> 31) | 0x80000000u;
    return u;
}

// ============ fused pre-pass: centroid partials / support & query norm+split ==
// blocks 0..255: centroid partial accumulation (64 rows each)
// blocks 256..767: support rows -> norm, yy, tiled f16 hi/lo (32 rows/block)
// blocks 768..831: query rows  -> norm, tiled f16 hi/lo (32 rows/block)
// Two-phase: (1) per-wave row norm + packed f16x8 LDS staging,
//            (2) plane-contiguous 512B-per-plane global write-out.
#define PADH 520   // LDS row stride in halves (bank-decorrelated, 16B aligned)

__global__ __launch_bounds__(256) void k_pre(
    const float* __restrict__ z, const float* __restrict__ supports,
    const float* __restrict__ labels,
    float* __restrict__ part, float* __restrict__ pcnt,
    float* __restrict__ yy,
    _Float16* __restrict__ suph, _Float16* __restrict__ supl,
    _Float16* __restrict__ znh, _Float16* __restrict__ znl)
{
    __shared__ __align__(16) char sbuf[66560];   // 65 KB, role-aliased
    const int tid = threadIdx.x;
    const int bid = blockIdx.x;
    const int w = tid >> 6, lane = tid & 63;

    if (bid < 256) {
        float* acc  = (float*)sbuf;              // 34,816 B
        float* lcnt = (float*)(sbuf + 34816);    // 68 B
        int*   lcls = (int*)(sbuf + 34944);      // 256 B
        for (int i = tid; i < C_CLS * DIM; i += 256) acc[i] = 0.f;
        if (tid < C_CLS) lcnt[tid] = 0.f;
        __syncthreads();
        if (tid < 64) {
            const int n = bid * 64 + tid;
            float best = labels[n * C_CLS + 0];
            int bc = 0;
            #pragma unroll
            for (int c = 1; c < C_CLS; ++c) {
                float v = labels[n * C_CLS + c];
                if (v > best) { best = v; bc = c; }
            }
            lcls[tid] = bc;
            atomicAdd(&lcnt[bc], best);   // best == 1.0 (one-hot)
        }
        __syncthreads();
        const int d0 = tid, d1 = tid + 256;
        const int base = bid * 64;
        for (int r = 0; r < 64; ++r) {
            const int c = lcls[r];
            const float* srow = supports + (size_t)(base + r) * DIM;
            acc[c * DIM + d0] += srow[d0];
            acc[c * DIM + d1] += srow[d1];
        }
        __syncthreads();
        float* pout = part + (size_t)bid * (C_CLS * DIM);
        for (int i = tid; i < C_CLS * DIM; i += 256) pout[i] = acc[i];
        if (tid < C_CLS) pcnt[bid * 32 + tid] = lcnt[tid];
        return;
    }

    _Float16* ldsH = (_Float16*)sbuf;            // 32 x PADH halves
    _Float16* ldsL = (_Float16*)(sbuf + 33280);

    const bool isq = (bid >= 768);
    const int rb = isq ? (bid - 768) : (bid - 256);
    const int NR = isq ? B_Q : N_S;
    const int n0 = rb * 32;
    const float* src = isq ? z : supports;

    // phase 1: each wave norms+splits 8 rows (lane owns k = lane*8 .. +8)
    #pragma unroll
    for (int i = 0; i < 8; ++i) {
        const int row = w * 8 + i;
        const float* srow = src + (size_t)(n0 + row) * DIM + lane * 8;
        float s[8];
        *(float4*)(s)     = *(const float4*)(srow);
        *(float4*)(s + 4) = *(const float4*)(srow + 4);
        float ss = 0.f;
        #pragma unroll
        for (int j = 0; j < 8; ++j) ss += s[j] * s[j];
        #pragma unroll
        for (int m = 1; m < 64; m <<= 1) ss += __shfl_xor(ss, m, 64);
        const float inv = 1.0f / fmaxf(sqrtf(ss), EPSF);
        f16x8 hi, lo;
        float y2 = 0.f;
        #pragma unroll
        for (int j = 0; j < 8; ++j) {
            const float v = s[j] * inv;
            y2 += v * v;
            const _Float16 hh = (_Float16)v;
            hi[j] = hh;
            lo[j] = (_Float16)(v - (float)hh);
        }
        *(f16x8*)(ldsH + row * PADH + lane * 8) = hi;
        *(f16x8*)(ldsL + row * PADH + lane * 8) = lo;
        if (!isq) {
            #pragma unroll
            for (int m = 1; m < 64; m <<= 1) y2 += __shfl_xor(y2, m, 64);
            if (lane == 0) yy[n0 + row] = y2;
        }
    }
    __syncthreads();

    // phase 2: plane-contiguous write-out (512 B per plane per block)
    _Float16* dstH = isq ? znh : suph;
    _Float16* dstL = isq ? znl : supl;
    #pragma unroll
    for (int it = 0; it < 8; ++it) {
        const int g = it * 8 + w * 2 + (lane >> 5);   // 0..63, all distinct
        const int row = lane & 31;
        const f16x8 hv = *(const f16x8*)(ldsH + row * PADH + g * 8);
        const f16x8 lv = *(const f16x8*)(ldsL + row * PADH + g * 8);
        const size_t off = ((size_t)g * NR + n0 + row) * 8;
        *(f16x8*)(dstH + off) = hv;
        *(f16x8*)(dstL + off) = lv;
    }
}

// ============== centroid finalize: normalize + split-f16 tiled ===============
// grid 32: blocks >= 17 just zero-pad the tiled centroid rows.
__global__ __launch_bounds__(256) void k_centroid_fin(
    const float* __restrict__ part, const float* __restrict__ pcnt,
    _Float16* __restrict__ cnh, _Float16* __restrict__ cnl)
{
    __shared__ float red[4];
    const int c = blockIdx.x, tid = threadIdx.x;
    if (c >= C_CLS) {
        if (tid < 64) {
            f16x8 zz = {};
            *(f16x8*)(cnh + ((size_t)tid * 32 + c) * 8) = zz;
            *(f16x8*)(cnl + ((size_t)tid * 32 + c) * 8) = zz;
        }
        return;
    }
    float cntv = 0.f;
    for (int b = 0; b < 256; ++b) cntv += pcnt[b * 32 + c];
    const float denc = cntv + EPSF;
    float v0 = 0.f, v1 = 0.f;
    for (int b = 0; b < 256; ++b) {
        const float* pb = part + (size_t)b * (C_CLS * DIM) + c * DIM;
        v0 += pb[tid];
        v1 += pb[tid + 256];
    }
    v0 /= denc;
    v1 /= denc;
    float ss = v0 * v0 + v1 * v1;
    #pragma unroll
    for (int m = 1; m < 64; m <<= 1) ss += __shfl_xor(ss, m, 64);
    if ((tid & 63) == 0) red[tid >> 6] = ss;
    __syncthreads();
    const float tot = red[0] + red[1] + red[2] + red[3];
    const float den = fmaxf(sqrtf(tot), EPSF);
    const float r0 = v0 / den, r1 = v1 / den;
    {
        const _Float16 h0 = (_Float16)r0;
        cnh[((size_t)(tid >> 3) * 32 + c) * 8 + (tid & 7)] = h0;
        cnl[((size_t)(tid >> 3) * 32 + c) * 8 + (tid & 7)] = (_Float16)(r0 - (float)h0);
        const int d1 = tid + 256;
        const _Float16 h1 = (_Float16)r1;
        cnh[((size_t)(d1 >> 3) * 32 + c) * 8 + (d1 & 7)] = h1;
        cnl[((size_t)(d1 >> 3) * 32 + c) * 8 + (d1 & 7)] = (_Float16)(r1 - (float)h1);
    }
}

// ====== MFMA score GEMM + sort-net top-8 (+temp_labels & query-logits) =======
// blocks 0..127:   temp_labels (tl = TAU*(Yn.cn) -> argmax cls + softmax p)
// blocks 128..143: query logits (TAU*(Zn.cn) -> out[0..B*C))
// blocks 144..1167: score blocks, XCD-swizzled: xcd = local&7 owns bn range
//   [8*xcd, 8*xcd+8) so each XCD's B working set fits its L2.
#define MFMA16(a, b, c) __builtin_amdgcn_mfma_f32_32x32x16_f16(a, b, c, 0, 0, 0)

__global__ __launch_bounds__(256, 2) void k_score_mfma(
    const _Float16* __restrict__ znh, const _Float16* __restrict__ znl,
    const _Float16* __restrict__ suph, const _Float16* __restrict__ supl,
    const _Float16* __restrict__ cnh, const _Float16* __restrict__ cnl,
    const float* __restrict__ yy, unsigned long long* __restrict__ cand,
    int* __restrict__ cls, float* __restrict__ pout, float* __restrict__ out)
{
    __shared__ __align__(16) float sww[4 * 16 * 129];   // 33 KB per-wave scratch

    const int tid = threadIdx.x;
    const int w = tid >> 6, l = tid & 63;
    const int h = l >> 5, ln = l & 31;
    const int blk = (int)blockIdx.x;

    const char* sh_c = (const char*)suph;
    const char* sl_c = (const char*)supl;

    if (blk < 144) {
        // ---- tl / ql blocks: 128-row GEMM vs centroids, double-buffered ----
        const bool isq = (blk >= 128);
        const int b2 = isq ? blk - 128 : blk;
        const int NR = isq ? B_Q : N_S;
        const char* rh_c = isq ? (const char*)znh : sh_c;
        const char* rl_c = isq ? (const char*)znl : sl_c;
        const char* ch_c = (const char*)cnh;
        const char* cl_c = (const char*)cnl;
        const int n0 = b2 * 128 + w * 32;

        f32x16 acc;
        #pragma unroll
        for (int e = 0; e < 16; ++e) acc[e] = 0.f;

        f16x8 ah[2], al[2], bh2[2], bl2[2];
        {
            const int g = h;
            ah[0]  = *(const f16x8*)(rh_c + (size_t)(g * NR + n0 + ln) * 16);
            al[0]  = *(const f16x8*)(rl_c + (size_t)(g * NR + n0 + ln) * 16);
            bh2[0] = *(const f16x8*)(ch_c + (size_t)(g * 32 + ln) * 16);
            bl2[0] = *(const f16x8*)(cl_c + (size_t)(g * 32 + ln) * 16);
        }
        for (int c = 0; c < 32; ++c) {
            const int cur = c & 1;
            if (c + 1 < 32) {
                const int g = 2 * (c + 1) + h;
                ah[cur ^ 1]  = *(const f16x8*)(rh_c + (size_t)(g * NR + n0 + ln) * 16);
                al[cur ^ 1]  = *(const f16x8*)(rl_c + (size_t)(g * NR + n0 + ln) * 16);
                bh2[cur ^ 1] = *(const f16x8*)(ch_c + (size_t)(g * 32 + ln) * 16);
                bl2[cur ^ 1] = *(const f16x8*)(cl_c + (size_t)(g * 32 + ln) * 16);
            }
            acc = MFMA16(ah[cur], bh2[cur], acc);
            acc = MFMA16(ah[cur], bl2[cur], acc);
            acc = MFMA16(al[cur], bh2[cur], acc);
        }
        float* sw = sww + w * (32 * 33);
        #pragma unroll
        for (int e = 0; e < 16; ++e) {
            const int row = (e & 3) + 8 * (e >> 2) + 4 * h;
            sw[row * 33 + ln] = acc[e];
        }
        __builtin_amdgcn_s_waitcnt(0);   // drain LDS writes before cross-half read
        if (l < 32) {
            const int n = n0 + l;
            if (isq) {
                #pragma unroll
                for (int c = 0; c < C_CLS; ++c)
                    out[n * C_CLS + c] = TAU_F * sw[l * 33 + c];
            } else {
                float tl[C_CLS];
                float mx = -FLT_MAX;
                int am = 0;
                #pragma unroll
                for (int c = 0; c < C_CLS; ++c) {
                    tl[c] = TAU_F * sw[l * 33 + c];
                    if (tl[c] > mx) { mx = tl[c]; am = c; }
                }
                float sum = 0.f;
                float e[C_CLS];
                #pragma unroll
                for (int c = 0; c < C_CLS; ++c) { e[c] = expf(tl[c] - mx); sum += e[c]; }
                cls[n] = am;
                #pragma unroll
                for (int c = 0; c < C_CLS; ++c) pout[n * C_CLS + c] = e[c] / sum;
            }
        }
        return;
    }

    // ---- score blocks: 128(q) x 256(s), barrier-free direct-global K-loop ----
    const int local = blk - 144;
    const int xcd = local & 7, sseq = local >> 3;
    const int bn = (xcd << 3) | (sseq >> 4);
    const int bm = sseq & 15;
    const int q0 = bm * 128, s0 = bn * 256;
    const int wm = w & 1, wn = w >> 1;

    const char* zh_c = (const char*)znh;
    const char* zl_c = (const char*)znl;

    unsigned int aoff[2], boff[4];
    #pragma unroll
    for (int t = 0; t < 2; ++t)
        aoff[t] = (unsigned int)(h * B_Q + q0 + wm * 64 + t * 32 + ln) * 16u;
    #pragma unroll
    for (int u = 0; u < 4; ++u)
        boff[u] = (unsigned int)(h * N_S + s0 + wn * 128 + u * 32 + ln) * 16u;

    f32x16 acc[2][4];
    #pragma unroll
    for (int t = 0; t < 2; ++t)
        #pragma unroll
        for (int u = 0; u < 4; ++u)
            #pragma unroll
            for (int e = 0; e < 16; ++e) acc[t][u][e] = 0.f;

    f16x8 ahb[2][2], alb[2][2], bh[4], bl[4];
    #pragma unroll
    for (int t = 0; t < 2; ++t) {
        ahb[0][t] = *(const f16x8*)(zh_c + aoff[t]);
        alb[0][t] = *(const f16x8*)(zl_c + aoff[t]);
        aoff[t] += 2u * B_Q * 16u;
    }
    #pragma unroll
    for (int u = 0; u < 4; ++u) {
        bh[u] = *(const f16x8*)(sh_c + boff[u]);
        bl[u] = *(const f16x8*)(sl_c + boff[u]);
        boff[u] += 2u * N_S * 16u;
    }

    auto do_chunk = [&](int ab, bool prefA, bool prefB) {
        if (prefA) {
            #pragma unroll
            for (int t = 0; t < 2; ++t) {
                ahb[ab ^ 1][t] = *(const f16x8*)(zh_c + aoff[t]);
                alb[ab ^ 1][t] = *(const f16x8*)(zl_c + aoff[t]);
                aoff[t] += 2u * B_Q * 16u;
            }
        }
        #pragma unroll
        for (int u = 0; u < 4; ++u) {
            acc[0][u] = MFMA16(ahb[ab][0], bh[u], acc[0][u]);
            acc[1][u] = MFMA16(ahb[ab][1], bh[u], acc[1][u]);
            acc[0][u] = MFMA16(ahb[ab][0], bl[u], acc[0][u]);
            acc[1][u] = MFMA16(ahb[ab][1], bl[u], acc[1][u]);
            acc[0][u] = MFMA16(alb[ab][0], bh[u], acc[0][u]);
            acc[1][u] = MFMA16(alb[ab][1], bh[u], acc[1][u]);
            if (prefB) {
                bh[u] = *(const f16x8*)(sh_c + boff[u]);
                bl[u] = *(const f16x8*)(sl_c + boff[u]);
                boff[u] += 2u * N_S * 16u;
            }
        }
    };

    for (int cp = 0; cp < 15; ++cp) {
        do_chunk(0, true, true);
        do_chunk(1, true, true);
    }
    do_chunk(0, true, true);
    do_chunk(1, false, false);

    // ---------------- epilogue: per-(q,128-col range) exact top-8 -------------
    float* sw = sww + w * (16 * 129);
    const int row16 = l & 15, seg = l >> 4;
    const int range = bn * 2 + wn;

    float yvh[4];
    #pragma unroll
    for (int u = 0; u < 4; ++u)
        yvh[u] = 0.5f * yy[s0 + wn * 128 + u * 32 + ln];

    #pragma unroll
    for (int pp = 0; pp < 4; ++pp) {
        const int t = pp >> 1, rb2 = (pp & 1) * 8;
        #pragma unroll
        for (int q8 = 0; q8 < 8; ++q8) {
            const int lr = (q8 & 3) + 8 * (q8 >> 2) + 4 * h;
            #pragma unroll
            for (int u = 0; u < 4; ++u)
                sw[lr * 129 + u * 32 + ln] = acc[t][u][rb2 + q8] - yvh[u];
        }
        const int colbase = s0 + wn * 128;
        unsigned long long A[8], G[8];
        #pragma unroll
        for (int e = 0; e < 8; ++e) {
            const int cc = seg * 32 + ((e + 8 * seg) & 31);
            const unsigned int sk = f32_sortable(sw[row16 * 129 + cc]);
            A[e] = ((unsigned long long)sk << 32) | (unsigned int)(~(colbase + cc));
        }
        sort8d(A);
        #pragma unroll
        for (int g = 1; g < 4; ++g) {
            #pragma unroll
            for (int e = 0; e < 8; ++e) {
                const int j = g * 8 + e;
                const int cc = seg * 32 + ((j + 8 * seg) & 31);
                const unsigned int sk = f32_sortable(sw[row16 * 129 + cc]);
                G[e] = ((unsigned long long)sk << 32) | (unsigned int)(~(colbase + cc));
            }
            sort8d(G);
            mrg8d(A, G);
        }
        #pragma unroll
        for (int r = 0; r < 8; ++r) G[r] = shfl_xor_u64(A[r], 16);
        mrg8d(A, G);
        #pragma unroll
        for (int r = 0; r < 8; ++r) G[r] = shfl_xor_u64(A[r], 32);
        mrg8d(A, G);

        if (seg == 0) {
            const int qg = q0 + wm * 64 + pp * 16 + row16;
            unsigned long long* dst = cand + (size_t)qg * 1024 + range * 8;
            #pragma unroll
            for (int r = 0; r < 8; ++r) dst[r] = A[r];
        }
    }
}

// ======================= final merge + targets/outputs =======================
__global__ __launch_bounds__(256) void k_merge_out(
    const unsigned long long* __restrict__ cand,
    const int* __restrict__ cls, const float* __restrict__ p,
    float* __restrict__ out)
{
    const int tid = threadIdx.x, w = tid >> 6, lane = tid & 63;
    const int q = blockIdx.x * 4 + w;

    unsigned long long A[8], G[8];
    #pragma unroll
    for (int j = 0; j < 8; ++j) A[j] = cand[(size_t)q * 1024 + j * 64 + lane];
    sort8d(A);
    #pragma unroll
    for (int j = 0; j < 8; ++j) G[j] = cand[(size_t)q * 1024 + (j + 8) * 64 + lane];
    sort8d(G);
    mrg8d(A, G);
    #pragma unroll
    for (int m = 1; m < 64; m <<= 1) {
        #pragma unroll
        for (int r = 0; r < 8; ++r) G[r] = shfl_xor_u64(A[r], m);
        mrg8d(A, G);
    }
    float tcnt = 0.f, osum = 0.f;
    #pragma unroll
    for (int r = 0; r < K_TOP; ++r) {
        const int bi = (int)(~(unsigned int)A[r]) & 0xFFFF;
        const int cw = cls[bi];
        if (lane < C_CLS) {
            osum += p[bi * C_CLS + lane];
            tcnt += (cw == lane) ? 1.0f : 0.f;
        }
    }
    float tt = tcnt, ot = osum;
    #pragma unroll
    for (int m = 1; m < 64; m <<= 1) {
        tt += __shfl_xor(tt, m, 64);
        ot += __shfl_xor(ot, m, 64);
    }
    if (lane < C_CLS) {
        out[(size_t)B_Q * C_CLS + q * C_CLS + lane]     = tcnt / (tt + EPSF);
        out[(size_t)2 * B_Q * C_CLS + q * C_CLS + lane] = osum / (ot + EPSF);
    }
}

// ======================= launcher =======================
extern "C" void kernel_launch(void* const* d_in, const int* in_sizes, int n_in,
                              void* d_out, int out_size, void* d_ws, size_t ws_size,
                              hipStream_t stream)
{
    const float* z        = (const float*)d_in[0];
    const float* supports = (const float*)d_in[1];
    const float* labels   = (const float*)d_in[2];
    float* ws  = (float*)d_ws;
    float* out = (float*)d_out;

    float*     part   = ws + WS_PARTA;
    float*     pcnt   = ws + WS_PCNTA;
    float*     yyv    = ws + WS_YY;
    int*       cls    = (int*)(ws + WS_CLS);
    float*     p      = ws + WS_P;
    unsigned long long* cand = (unsigned long long*)(ws + WS_CAND);
    _Float16*  cnh    = (_Float16*)(ws + WS_CNH);
    _Float16*  cnl    = (_Float16*)(ws + WS_CNL);
    _Float16*  znh    = (_Float16*)(ws + WS_ZNH);
    _Float16*  znl    = (_Float16*)(ws + WS_ZNL);
    _Float16*  suph   = (_Float16*)(ws + WS_SUPH);
    _Float16*  supl   = (_Float16*)(ws + WS_SUPL);

    hipLaunchKernelGGL(k_pre, dim3(832), dim3(256), 0, stream,
                       z, supports, labels, part, pcnt, yyv,
                       suph, supl, znh, znl);
    hipLaunchKernelGGL(k_centroid_fin, dim3(32), dim3(256), 0, stream,
                       part, pcnt, cnh, cnl);
    hipLaunchKernelGGL(k_score_mfma, dim3(1168), dim3(256), 0, stream,
                       znh, znl, suph, supl, cnh, cnl, yyv, cand, cls, p, out);
    hipLaunchKernelGGL(k_merge_out, dim3(512), dim3(256), 0, stream,
                       cand, cls, p, out);
}